// Round 5
// baseline (682.181 us; speedup 1.0000x reference)
//
#include <hip/hip_runtime.h>
#include <hip/hip_bf16.h>
#include <math.h>

#define BATCH 16384
#define NCAT 24

// log(1e-30f), log(16)
#define L30F  (-69.07755279f)
#define LOGKF (2.7725887f)

typedef __attribute__((ext_vector_type(8))) short short8;
typedef __attribute__((ext_vector_type(4))) float f32x4;

__device__ __forceinline__ float lae(float a, float b) {
    float m = fmaxf(a, b);
    return m + logf(expf(a - m) + expf(b - m));
}

__device__ __forceinline__ void glds16(const void* g, void* l) {
    __builtin_amdgcn_global_load_lds((const __attribute__((address_space(1))) void*)g,
                                     (__attribute__((address_space(3))) void*)l,
                                     16, 0, 0);
}

// ------------------- fused setup: 5x weight transpose + E0 + colconst + sched
// blocks [0,4000): weight transpose f32->bf16 (5 jobs)
// blocks [4000,8000): E0 bf16 timestep-embedding table (1000x1024)
// blocks [8000,8004): colconst[j] = proj_b[j] + L30F * sum_{r=16}^{399} proj_w[r][j]
// block 8004: schedules + acc zero
__global__ __launch_bounds__(256) void setup_all(
    const float* __restrict__ s0, const float* __restrict__ s1,
    const float* __restrict__ s2, const float* __restrict__ s3,
    const float* __restrict__ s4,
    __hip_bfloat16* __restrict__ d0, __hip_bfloat16* __restrict__ d1,
    __hip_bfloat16* __restrict__ d2, __hip_bfloat16* __restrict__ d3,
    __hip_bfloat16* __restrict__ d4,
    __hip_bfloat16* __restrict__ E0, const float* __restrict__ proj_w,
    const float* __restrict__ proj_b, float* __restrict__ colconst,
    float* __restrict__ sched, double* __restrict__ acc) {
    const int bid = blockIdx.x, tid = threadIdx.x;
    if (bid < 4000) {
        // weight transpose: W[K x Nw] f32 -> Wt[Npad x Kpad] bf16 (zero pad)
        const int boff[6] = {0, 1024, 2048, 2464, 3488, 4000};
        const int nxs[5]  = {32, 32, 32, 32, 16};
        const int Ks[5]   = {1024, 1024, 400, 1024, 1024};
        const int Kps[5]  = {1024, 1024, 416, 1024, 1024};
        const int Nws[5]  = {1024, 1024, 1024, 1024, 400};
        const int Nps[5]  = {1024, 1024, 1024, 1024, 512};
        int job = 0;
#pragma unroll
        for (int j = 1; j < 5; ++j) job += (bid >= boff[j]) ? 1 : 0;
        const float* W = (job == 0) ? s0 : (job == 1) ? s1 : (job == 2) ? s2
                         : (job == 3) ? s3 : s4;
        __hip_bfloat16* Wt = (job == 0) ? d0 : (job == 1) ? d1 : (job == 2) ? d2
                             : (job == 3) ? d3 : d4;
        const int lb = bid - boff[job];
        const int K = Ks[job], Kpad = Kps[job], Nw = Nws[job], Npad = Nps[job];
        const int n0 = (lb % nxs[job]) * 32, k0 = (lb / nxs[job]) * 32;
        __shared__ float t[32][33];
        int c = tid & 31, r8 = tid >> 5;
#pragma unroll
        for (int i = 0; i < 32; i += 8) {
            int k = k0 + r8 + i, n = n0 + c;
            t[r8 + i][c] = (n < Nw && k < K) ? W[(size_t)k * Nw + n] : 0.0f;
        }
        __syncthreads();
#pragma unroll
        for (int i = 0; i < 32; i += 8) {
            int n = n0 + r8 + i, k = k0 + c;
            if (n < Npad && k < Kpad) Wt[(size_t)n * Kpad + k] = __float2bfloat16(t[c][r8 + i]);
        }
    } else if (bid < 8000) {
        int gid = (bid - 4000) * 256 + tid;
        int t = gid >> 10, j = gid & 1023;
        int jj = (j < 512) ? j : j - 512;
        float freq = expf(-logf(10000.0f) * (float)jj / 512.0f);
        float arg = (float)t * freq;
        E0[gid] = __float2bfloat16((j < 512) ? cosf(arg) : sinf(arg));
    } else if (bid < 8004) {
        int j = (bid - 8000) * 256 + tid;
        float s = 0.0f;
        for (int r = 16; r < 400; ++r) s += proj_w[(size_t)r * 1024 + j];
        colconst[j] = proj_b[j] + L30F * s;
    } else {
        __shared__ double la_s[1000];
        __shared__ double lca_s[1000];
        const double PI = 3.14159265358979323846;
        for (int i = tid; i < 1000; i += 256) {
            double u0 = ((double)i / 1000.0 + 0.008) / 1.008 * PI * 0.5;
            double u1 = ((double)(i + 1) / 1000.0 + 0.008) / 1.008 * PI * 0.5;
            double c0 = cos(u0), c1 = cos(u1);
            double beta = 1.0 - (c1 * c1) / (c0 * c0);
            if (beta > 0.999) beta = 0.999;
            la_s[i] = log(1.0 - beta);
        }
        __syncthreads();
        if (tid == 0) {
            double run = 0.0;
            for (int i = 0; i < 1000; ++i) { run += la_s[i]; lca_s[i] = run; }
            *acc = 0.0;
        }
        __syncthreads();
        for (int i = tid; i < 1000; i += 256) {
            double la = la_s[i], lca = lca_s[i];
            sched[i]        = (float)la;
            sched[1000 + i] = (float)log(1.0 - exp(la) + 1e-40);
            sched[2000 + i] = (float)lca;
            sched[3000 + i] = (float)log(1.0 - exp(lca) + 1e-40);
            sched[4000 + i] = (float)sqrt(exp(lca));
            sched[5000 + i] = (float)sqrt(1.0 - exp(lca));
        }
    }
}

// ------------------------------------------------------------- reductions
__device__ __forceinline__ void block_reduce_add(double contrib, double* acc_out) {
    for (int off = 32; off > 0; off >>= 1)
        contrib += __shfl_down(contrib, off);
    __shared__ double wsum[4];
    int lane = threadIdx.x & 63, wv = threadIdx.x >> 6;
    if (lane == 0) wsum[wv] = contrib;
    __syncthreads();
    if (threadIdx.x == 0)
        atomicAdd(acc_out, wsum[0] + wsum[1] + wsum[2] + wsum[3]);
}

// ------------------------------------------------------------ bf16 MFMA GEMM
// C[M,Nreal] = epi(A[M,Kd] @ Bt^T + bias), A row-major bf16, Bt [Npad x Kd] bf16.
// TILE x TILE block tile, BK=32, 4 waves (2x2), FM x FM frags of 16x16x32 MFMA.
// XCD-aware swizzle. EPI: 0 = f32 store, 1 = silu + bf16, 2 = relu + bf16,
// 3 = +rowbias[tidx[m]] + bf16, 4 = fused categorical+gaussian loss (no store).
template <int EPI, int TILE>
__global__ __launch_bounds__(256) void gemm_mfma(
    const __hip_bfloat16* __restrict__ A, const __hip_bfloat16* __restrict__ Bt,
    const float* __restrict__ bias, void* __restrict__ Cout,
    int M, int Kd, int Nreal, int Cstride,
    const int* __restrict__ tidx, const float* __restrict__ rowbias,
    const int* __restrict__ x_cat, const int* __restrict__ t_in,
    const int* __restrict__ hot, const float* __restrict__ noise,
    const float* __restrict__ sched, double* __restrict__ acc_out) {
    constexpr int FM  = TILE / 32;   // MFMA frags per wave per dim
    constexpr int CPM = TILE / 16;   // 16-row staging chunks per matrix
    constexpr int CPW = TILE / 32;   // staging chunks per wave
    __shared__ __hip_bfloat16 As[TILE * 32];
    __shared__ __hip_bfloat16 Bs[TILE * 32];

    const int tid = threadIdx.x;
    const int lane = tid & 63, wave = tid >> 6;
    const int wm = wave >> 1, wn = wave & 1;

    // XCD swizzle (same-m n-blocks consecutive within one XCD)
    int mb, nb;
    {
        int nbx = gridDim.x, nby = gridDim.y;
        int b = blockIdx.y * nbx + blockIdx.x;
        if ((nby & 7) == 0) {
            int x = b & 7, g = b >> 3;
            nb = g % nbx;
            mb = x + 8 * (g / nbx);
        } else { mb = blockIdx.y; nb = blockIdx.x; }
    }
    const int m0 = mb * TILE, n0 = nb * TILE;

    const __hip_bfloat16* gsrc[CPW];
    char* ldst[CPW];
#pragma unroll
    for (int ii = 0; ii < CPW; ++ii) {
        int gc = wave * CPW + ii;
        int mat = gc / CPM, rem = gc % CPM;
        int row = rem * 16 + (lane >> 2);
        int col = (lane & 3) * 8;
        if (mat == 0) {
            int r = m0 + row; if (r > M - 1) r = M - 1;   // clamp; stores guarded
            gsrc[ii] = A + (size_t)r * Kd + col;
            ldst[ii] = (char*)As + rem * 1024;
        } else {
            int r = n0 + row;                             // Bt padded to tile
            gsrc[ii] = Bt + (size_t)r * Kd + col;
            ldst[ii] = (char*)Bs + rem * 1024;
        }
    }

    f32x4 acc[FM][FM] = {};
    const int q8 = (lane >> 4) * 8;
    const int l15 = lane & 15;

    for (int k0 = 0; k0 < Kd; k0 += 32) {
#pragma unroll
        for (int ii = 0; ii < CPW; ++ii) glds16(gsrc[ii] + k0, ldst[ii]);
        __syncthreads();
        short8 af[FM], bfr[FM];
#pragma unroll
        for (int i = 0; i < FM; ++i) {
            af[i]  = *(const short8*)(As + (size_t)(wm * (TILE / 2) + i * 16 + l15) * 32 + q8);
            bfr[i] = *(const short8*)(Bs + (size_t)(wn * (TILE / 2) + i * 16 + l15) * 32 + q8);
        }
#pragma unroll
        for (int i = 0; i < FM; ++i)
#pragma unroll
            for (int j = 0; j < FM; ++j)
                acc[i][j] = __builtin_amdgcn_mfma_f32_16x16x32_bf16(
                    af[i], bfr[j], acc[i][j], 0, 0, 0);
        __syncthreads();
    }

    if (EPI == 4) {
        // fused loss epilogue: each C frag = 16 rows x 16 k's of one category
        // (or the numeric block for n==0). Per reg-layer: 4 rows x 16 k's across
        // 64 lanes; logsumexps via width-16 shuffles; rest elementwise.
        double local = 0.0;
        const float* LOG_A = sched;
        const float* LOG_1M_A = sched + 1000;
        const float* LOG_CA = sched + 2000;
        const float* LOG_1M_CA = sched + 3000;
        const int q = lane >> 4;
#pragma unroll
        for (int i = 0; i < FM; ++i) {
#pragma unroll
            for (int j = 0; j < FM; ++j) {
                int n = n0 + wn * (TILE / 2) + j * 16;   // frag base col (16-aligned)
                if (n >= 400) continue;                  // zero-pad cols
                float bv = bias[n + l15];
#pragma unroll
                for (int r = 0; r < 4; ++r) {
                    int m = m0 + wm * (TILE / 2) + i * 16 + q * 4 + r;
                    float v = acc[i][j][r] + bv;
                    if (n == 0) {
                        float d = noise[(size_t)m * 16 + l15] - v;
                        local += (double)(d * d) * (1.0 / (16.0 * BATCH));
                    } else {
                        int c = (n - 16) >> 4;
                        int t = t_in[m];
                        int xc = x_cat[m * 24 + c];
                        int s = hot[m * 24 + c];
                        // lse of logits over 16 k's
                        float mx = v;
#pragma unroll
                        for (int msk = 1; msk < 16; msk <<= 1)
                            mx = fmaxf(mx, __shfl_xor(mx, msk, 16));
                        float sm = expf(v - mx);
#pragma unroll
                        for (int msk = 1; msk < 16; msk <<= 1)
                            sm += __shfl_xor(sm, msk, 16);
                        float lse = mx + logf(sm);
                        int tm1 = (t > 0) ? t - 1 : 0;
                        float lca1 = LOG_CA[tm1];
                        float l1m1 = LOG_1M_CA[tm1] - LOGKF;
                        float la = LOG_A[t];
                        float l1a = LOG_1M_A[t] - LOGKF;
                        float qh = lae(la, l1a);
                        float qo = lae(L30F + la, l1a);
                        float levh = (t == 0) ? 0.0f : lae(lca1, l1m1);
                        float levo = (t == 0) ? L30F : lae(L30F + lca1, l1m1);
                        float lxh = v - lse;
                        float lev = (t == 0) ? lxh : lae(lxh + lca1, l1m1);
                        float qk = (l15 == s) ? qh : qo;
                        float un = lev + qk;
                        float ut = ((l15 == xc) ? levh : levo) + qk;
                        float mu = un, mt2 = ut;
#pragma unroll
                        for (int msk = 1; msk < 16; msk <<= 1) {
                            mu = fmaxf(mu, __shfl_xor(mu, msk, 16));
                            mt2 = fmaxf(mt2, __shfl_xor(mt2, msk, 16));
                        }
                        float su = expf(un - mu), st = expf(ut - mt2);
#pragma unroll
                        for (int msk = 1; msk < 16; msk <<= 1) {
                            su += __shfl_xor(su, msk, 16);
                            st += __shfl_xor(st, msk, 16);
                        }
                        float lsu = mu + logf(su), lst = mt2 + logf(st);
                        float lmp = un - lsu, ltp = ut - lst;
                        float term = (t == 0)
                            ? -((l15 == xc) ? 1.0f : 1e-30f) * lmp
                            : expf(ltp) * (ltp - lmp);
                        local += (double)term * (1.0 / (24.0 * BATCH));
                    }
                }
            }
        }
        block_reduce_add(local, acc_out);
        return;
    }

#pragma unroll
    for (int i = 0; i < FM; ++i) {
        int mbase = m0 + wm * (TILE / 2) + i * 16 + (lane >> 4) * 4;
#pragma unroll
        for (int j = 0; j < FM; ++j) {
            int n = n0 + wn * (TILE / 2) + j * 16 + l15;
            if (n >= Nreal) continue;
            float bv = bias[n];
#pragma unroll
            for (int r = 0; r < 4; ++r) {
                int m = mbase + r;
                if (m >= M) continue;
                float v = acc[i][j][r] + bv;
                if (EPI == 1) v = v / (1.0f + expf(-v));
                if (EPI == 2) v = fmaxf(v, 0.0f);
                if (EPI == 3) v += rowbias[(size_t)tidx[m] * 1024 + n];
                if (EPI == 0)
                    ((float*)Cout)[(size_t)m * Cstride + n] = v;
                else
                    ((__hip_bfloat16*)Cout)[(size_t)m * Cstride + n] = __float2bfloat16(v);
            }
        }
    }
}

// ----------------------- per-row prep: gumbel argmax + build X[B x 416] bf16
// X = [x_num_t (16) | delta-onehot*69.0776 (384) | zeros (16)]
__global__ __launch_bounds__(256) void prep_x(
    const float* __restrict__ x_num, const int* __restrict__ x_cat,
    const int* __restrict__ t_in, const float* __restrict__ noise,
    const float* __restrict__ gum, const float* __restrict__ sched,
    __hip_bfloat16* __restrict__ X, int* __restrict__ hot) {
    __shared__ float xnt[16][16];
    __shared__ int sh_hot[16][24];
    __shared__ int sh_t[16];
    const int b0 = blockIdx.x * 16;
    const int tid = threadIdx.x;
    const float* LOG_CA = sched + 2000;
    const float* LOG_1M_CA = sched + 3000;
    const float* SQ_AC = sched + 4000;
    const float* SQ_1M = sched + 5000;
    if (tid < 16) sh_t[tid] = t_in[b0 + tid];
    __syncthreads();
    {
        int r = tid >> 4, i = tid & 15;
        int t = sh_t[r];
        xnt[r][i] = SQ_AC[t] * x_num[(size_t)(b0 + r) * 16 + i] +
                    SQ_1M[t] * noise[(size_t)(b0 + r) * 16 + i];
    }
    for (int task = tid; task < 16 * 24; task += 256) {
        int r = task / 24, c = task - r * 24;
        int t = sh_t[r];
        int xc = x_cat[(size_t)(b0 + r) * 24 + c];
        float l1 = LOG_1M_CA[t] - LOGKF;
        float lca = LOG_CA[t];
        float vh = lae(lca, l1);
        float vo = lae(L30F + lca, l1);
        const float* gu = gum + (size_t)(b0 + r) * 384 + c * 16;
        float best = -3.0e38f;
        int bi = 0;
#pragma unroll
        for (int k = 0; k < 16; ++k) {
            float g = -logf(-logf(gu[k] + 1e-30f) + 1e-30f);
            float v = g + ((k == xc) ? vh : vo);
            if (v > best) { best = v; bi = k; }
        }
        sh_hot[r][c] = bi;
        hot[(size_t)(b0 + r) * 24 + c] = bi;
    }
    __syncthreads();
    const float DELTA = 69.07755279f;  // -L30F
#pragma unroll
    for (int it = 0; it < 4; ++it) {
        int idx = it * 256 + tid;          // need 16*52 = 832 short8 stores
        if (idx < 832) {
            int r = idx / 52, jc = idx - r * 52;
            int j0 = jc * 8;
            __hip_bfloat16 v[8];
#pragma unroll
            for (int qq = 0; qq < 8; ++qq) {
                int j = j0 + qq;
                float f = 0.0f;
                if (j < 16) {
                    f = xnt[r][j];
                } else if (j < 400) {
                    int c = (j - 16) >> 4, k = (j - 16) & 15;
                    f = (sh_hot[r][c] == k) ? DELTA : 0.0f;
                }
                v[qq] = __float2bfloat16(f);
            }
            *(short8*)(X + (size_t)(b0 + r) * 416 + j0) = *(const short8*)v;
        }
    }
}

__global__ void finalize_kernel(const double* __restrict__ acc,
                                const float* __restrict__ sched,
                                float* __restrict__ out) {
    // kl_prior is identical for every (sample, category): add once.
    float lcaT = sched[2999];
    float l1mT = sched[3999] - LOGKF;
    float ph = lae(lcaT, l1mT);
    float po = lae(L30F + lcaT, l1mT);
    float prior = expf(ph) * (ph + LOGKF) + 15.0f * expf(po) * (po + LOGKF);
    out[0] = (float)(*acc + (double)prior);
}

extern "C" void kernel_launch(void* const* d_in, const int* in_sizes, int n_in,
                              void* d_out, int out_size, void* d_ws, size_t ws_size,
                              hipStream_t stream) {
    const float* x_num  = (const float*)d_in[0];
    const int*   x_cat  = (const int*)d_in[1];
    const int*   t_in   = (const int*)d_in[2];
    const float* noise  = (const float*)d_in[3];
    const float* gum    = (const float*)d_in[4];
    const float* te_w1  = (const float*)d_in[5];
    const float* te_b1  = (const float*)d_in[6];
    const float* te_w2  = (const float*)d_in[7];
    const float* te_b2  = (const float*)d_in[8];
    const float* proj_w = (const float*)d_in[9];
    const float* proj_b = (const float*)d_in[10];
    const float* mlp_w1 = (const float*)d_in[11];
    const float* mlp_b1 = (const float*)d_in[12];
    const float* mlp_w2 = (const float*)d_in[13];
    const float* mlp_b2 = (const float*)d_in[14];
    float* out = (float*)d_out;

    char* w = (char*)d_ws;
    size_t off = 0;
    auto alloc = [&](size_t bytes) {
        void* p = w + off;
        off += (bytes + 1023) & ~(size_t)1023;
        return p;
    };
    double* acc     = (double*)alloc(1024);
    float* sched    = (float*)alloc(6 * 1000 * 4);
    int*   hot      = (int*)alloc((size_t)BATCH * 24 * 4);
    float* colconst = (float*)alloc(1024 * 4);
    __hip_bfloat16* E0   = (__hip_bfloat16*)alloc((size_t)1024 * 1024 * 2);
    __hip_bfloat16* E1   = (__hip_bfloat16*)alloc((size_t)1024 * 1024 * 2);
    float* EMB           = (float*)alloc((size_t)1000 * 1024 * 4);
    __hip_bfloat16* tw1t = (__hip_bfloat16*)alloc((size_t)1024 * 1024 * 2);
    __hip_bfloat16* tw2t = (__hip_bfloat16*)alloc((size_t)1024 * 1024 * 2);
    __hip_bfloat16* pwt  = (__hip_bfloat16*)alloc((size_t)1024 * 416 * 2);
    __hip_bfloat16* w1t  = (__hip_bfloat16*)alloc((size_t)1024 * 1024 * 2);
    __hip_bfloat16* w2t  = (__hip_bfloat16*)alloc((size_t)512 * 1024 * 2);
    __hip_bfloat16* X    = (__hip_bfloat16*)alloc((size_t)BATCH * 416 * 2);
    __hip_bfloat16* h    = (__hip_bfloat16*)alloc((size_t)BATCH * 1024 * 2);
    __hip_bfloat16* R    = (__hip_bfloat16*)alloc((size_t)BATCH * 1024 * 2);

    // setup: 5 weight transposes + E0 table + colconst + schedules (one launch)
    setup_all<<<8005, 256, 0, stream>>>(te_w1, te_w2, proj_w, mlp_w1, mlp_w2,
                                        tw1t, tw2t, pwt, w1t, w2t,
                                        E0, proj_w, proj_b, colconst, sched, acc);
    // X + hot
    prep_x<<<BATCH / 16, 256, 0, stream>>>(x_num, x_cat, t_in, noise, gum, sched, X, hot);
    // E1 = silu(E0 @ te_w1 + te_b1)   [bf16 out]
    gemm_mfma<1, 64><<<dim3(16, 16), 256, 0, stream>>>(
        E0, tw1t, te_b1, E1, 1000, 1024, 1024, 1024,
        nullptr, nullptr, nullptr, nullptr, nullptr, nullptr, nullptr, nullptr);
    // EMB = E1 @ te_w2 + te_b2        [f32 out]
    gemm_mfma<0, 64><<<dim3(16, 16), 256, 0, stream>>>(
        E1, tw2t, te_b2, EMB, 1000, 1024, 1024, 1024,
        nullptr, nullptr, nullptr, nullptr, nullptr, nullptr, nullptr, nullptr);
    // h = X @ proj_w^T + colconst + EMB[t]   [bf16 out, K=416]
    gemm_mfma<3, 128><<<dim3(8, 128), 256, 0, stream>>>(
        X, pwt, colconst, h, BATCH, 416, 1024, 1024,
        t_in, EMB, nullptr, nullptr, nullptr, nullptr, nullptr, nullptr);
    // R = relu(h @ mlp_w1 + mlp_b1)   [bf16 out]
    gemm_mfma<2, 128><<<dim3(8, 128), 256, 0, stream>>>(
        h, w1t, mlp_b1, R, BATCH, 1024, 1024, 1024,
        nullptr, nullptr, nullptr, nullptr, nullptr, nullptr, nullptr, nullptr);
    // fused: (R @ mlp_w2 + mlp_b2) -> categorical + gaussian loss (no store)
    gemm_mfma<4, 128><<<dim3(4, 128), 256, 0, stream>>>(
        R, w2t, mlp_b2, nullptr, BATCH, 1024, 400, 0,
        nullptr, nullptr, x_cat, t_in, hot, noise, sched, acc);
    finalize_kernel<<<1, 1, 0, stream>>>(acc, sched, out);
}

// Round 6
// 391.053 us; speedup vs baseline: 1.7445x; 1.7445x over previous
//
#include <hip/hip_runtime.h>
#include <hip/hip_bf16.h>
#include <math.h>

#define BATCH 16384
#define NCAT 24

// log(1e-30f), log(16)
#define L30F  (-69.07755279f)
#define LOGKF (2.7725887f)

typedef __attribute__((ext_vector_type(8))) short short8;
typedef __attribute__((ext_vector_type(4))) float f32x4;

__device__ __forceinline__ float lae(float a, float b) {
    float m = fmaxf(a, b);
    return m + logf(expf(a - m) + expf(b - m));
}

__device__ __forceinline__ void glds16(const void* g, void* l) {
    __builtin_amdgcn_global_load_lds((const __attribute__((address_space(1))) void*)g,
                                     (__attribute__((address_space(3))) void*)l,
                                     16, 0, 0);
}

// ------------------- fused setup: 5x weight transpose + E0 + colconst + sched
__global__ __launch_bounds__(256) void setup_all(
    const float* __restrict__ s0, const float* __restrict__ s1,
    const float* __restrict__ s2, const float* __restrict__ s3,
    const float* __restrict__ s4,
    __hip_bfloat16* __restrict__ d0, __hip_bfloat16* __restrict__ d1,
    __hip_bfloat16* __restrict__ d2, __hip_bfloat16* __restrict__ d3,
    __hip_bfloat16* __restrict__ d4,
    __hip_bfloat16* __restrict__ E0, const float* __restrict__ proj_w,
    const float* __restrict__ proj_b, float* __restrict__ colconst,
    float* __restrict__ sched, double* __restrict__ acc) {
    const int bid = blockIdx.x, tid = threadIdx.x;
    if (bid < 4000) {
        // weight transpose: W[K x Nw] f32 -> Wt[Npad x Kpad] bf16 (zero pad)
        const int boff[6] = {0, 1024, 2048, 2464, 3488, 4000};
        const int nxs[5]  = {32, 32, 32, 32, 16};
        const int Ks[5]   = {1024, 1024, 400, 1024, 1024};
        const int Kps[5]  = {1024, 1024, 416, 1024, 1024};
        const int Nws[5]  = {1024, 1024, 1024, 1024, 400};
        const int Nps[5]  = {1024, 1024, 1024, 1024, 512};
        int job = 0;
#pragma unroll
        for (int j = 1; j < 5; ++j) job += (bid >= boff[j]) ? 1 : 0;
        const float* W = (job == 0) ? s0 : (job == 1) ? s1 : (job == 2) ? s2
                         : (job == 3) ? s3 : s4;
        __hip_bfloat16* Wt = (job == 0) ? d0 : (job == 1) ? d1 : (job == 2) ? d2
                             : (job == 3) ? d3 : d4;
        const int lb = bid - boff[job];
        const int K = Ks[job], Kpad = Kps[job], Nw = Nws[job], Npad = Nps[job];
        const int n0 = (lb % nxs[job]) * 32, k0 = (lb / nxs[job]) * 32;
        __shared__ float t[32][33];
        int c = tid & 31, r8 = tid >> 5;
#pragma unroll
        for (int i = 0; i < 32; i += 8) {
            int k = k0 + r8 + i, n = n0 + c;
            t[r8 + i][c] = (n < Nw && k < K) ? W[(size_t)k * Nw + n] : 0.0f;
        }
        __syncthreads();
#pragma unroll
        for (int i = 0; i < 32; i += 8) {
            int n = n0 + r8 + i, k = k0 + c;
            if (n < Npad && k < Kpad) Wt[(size_t)n * Kpad + k] = __float2bfloat16(t[c][r8 + i]);
        }
    } else if (bid < 8000) {
        int gid = (bid - 4000) * 256 + tid;
        int t = gid >> 10, j = gid & 1023;
        int jj = (j < 512) ? j : j - 512;
        float freq = expf(-logf(10000.0f) * (float)jj / 512.0f);
        float arg = (float)t * freq;
        E0[gid] = __float2bfloat16((j < 512) ? cosf(arg) : sinf(arg));
    } else if (bid < 8004) {
        int j = (bid - 8000) * 256 + tid;
        float s = 0.0f;
        for (int r = 16; r < 400; ++r) s += proj_w[(size_t)r * 1024 + j];
        colconst[j] = proj_b[j] + L30F * s;
    } else {
        __shared__ double la_s[1000];
        __shared__ double lca_s[1000];
        const double PI = 3.14159265358979323846;
        for (int i = tid; i < 1000; i += 256) {
            double u0 = ((double)i / 1000.0 + 0.008) / 1.008 * PI * 0.5;
            double u1 = ((double)(i + 1) / 1000.0 + 0.008) / 1.008 * PI * 0.5;
            double c0 = cos(u0), c1 = cos(u1);
            double beta = 1.0 - (c1 * c1) / (c0 * c0);
            if (beta > 0.999) beta = 0.999;
            la_s[i] = log(1.0 - beta);
        }
        __syncthreads();
        if (tid == 0) {
            double run = 0.0;
            for (int i = 0; i < 1000; ++i) { run += la_s[i]; lca_s[i] = run; }
            *acc = 0.0;
        }
        __syncthreads();
        for (int i = tid; i < 1000; i += 256) {
            double la = la_s[i], lca = lca_s[i];
            sched[i]        = (float)la;
            sched[1000 + i] = (float)log(1.0 - exp(la) + 1e-40);
            sched[2000 + i] = (float)lca;
            sched[3000 + i] = (float)log(1.0 - exp(lca) + 1e-40);
            sched[4000 + i] = (float)sqrt(exp(lca));
            sched[5000 + i] = (float)sqrt(1.0 - exp(lca));
        }
    }
}

// ------------------------------------------------------------ bf16 MFMA GEMM
// C[M,Nreal] = epi(A[M,Kd] @ Bt^T + bias), A row-major bf16, Bt [Npad x Kd] bf16.
// TILE x TILE block tile, BK=32, 4 waves (2x2), FM x FM frags of 16x16x32 MFMA.
// XCD-aware swizzle. EPI: 0 = f32 store, 1 = silu + bf16, 2 = relu + bf16,
// 3 = +rowbias[tidx[m]] + bf16,
// 4 = fused loss: acc -> LDS scoreboard -> per-(row,cat) loss (no store).
template <int EPI, int TILE>
__global__ __launch_bounds__(256) void gemm_mfma(
    const __hip_bfloat16* __restrict__ A, const __hip_bfloat16* __restrict__ Bt,
    const float* __restrict__ bias, void* __restrict__ Cout,
    int M, int Kd, int Nreal, int Cstride,
    const int* __restrict__ tidx, const float* __restrict__ rowbias,
    const int* __restrict__ x_cat, const int* __restrict__ t_in,
    const int* __restrict__ hot, const float* __restrict__ noise,
    const float* __restrict__ sched, double* __restrict__ acc_out) {
    constexpr int FM  = TILE / 32;   // MFMA frags per wave per dim
    constexpr int CPM = TILE / 16;   // 16-row staging chunks per matrix
    constexpr int CPW = TILE / 32;   // staging chunks per wave
    constexpr int SMEM_BYTES = (EPI == 4) ? 65536 : (4 * TILE * 32);
    __shared__ __align__(16) char SMEM[SMEM_BYTES];
    __hip_bfloat16* As = (__hip_bfloat16*)SMEM;
    __hip_bfloat16* Bs = As + TILE * 32;

    const int tid = threadIdx.x;
    const int lane = tid & 63, wave = tid >> 6;
    const int wm = wave >> 1, wn = wave & 1;

    // XCD swizzle (same-m n-blocks consecutive within one XCD)
    int mb, nb;
    {
        int nbx = gridDim.x, nby = gridDim.y;
        int b = blockIdx.y * nbx + blockIdx.x;
        if ((nby & 7) == 0) {
            int x = b & 7, g = b >> 3;
            nb = g % nbx;
            mb = x + 8 * (g / nbx);
        } else { mb = blockIdx.y; nb = blockIdx.x; }
    }
    const int m0 = mb * TILE, n0 = nb * TILE;

    const __hip_bfloat16* gsrc[CPW];
    char* ldst[CPW];
#pragma unroll
    for (int ii = 0; ii < CPW; ++ii) {
        int gc = wave * CPW + ii;
        int mat = gc / CPM, rem = gc % CPM;
        int row = rem * 16 + (lane >> 2);
        int col = (lane & 3) * 8;
        if (mat == 0) {
            int r = m0 + row; if (r > M - 1) r = M - 1;   // clamp; stores guarded
            gsrc[ii] = A + (size_t)r * Kd + col;
            ldst[ii] = (char*)As + rem * 1024;
        } else {
            int r = n0 + row;                             // Bt padded to tile
            gsrc[ii] = Bt + (size_t)r * Kd + col;
            ldst[ii] = (char*)Bs + rem * 1024;
        }
    }

    f32x4 acc[FM][FM] = {};
    const int q8 = (lane >> 4) * 8;
    const int l15 = lane & 15;

    for (int k0 = 0; k0 < Kd; k0 += 32) {
#pragma unroll
        for (int ii = 0; ii < CPW; ++ii) glds16(gsrc[ii] + k0, ldst[ii]);
        __syncthreads();
        short8 af[FM], bfr[FM];
#pragma unroll
        for (int i = 0; i < FM; ++i) {
            af[i]  = *(const short8*)(As + (size_t)(wm * (TILE / 2) + i * 16 + l15) * 32 + q8);
            bfr[i] = *(const short8*)(Bs + (size_t)(wn * (TILE / 2) + i * 16 + l15) * 32 + q8);
        }
#pragma unroll
        for (int i = 0; i < FM; ++i)
#pragma unroll
            for (int j = 0; j < FM; ++j)
                acc[i][j] = __builtin_amdgcn_mfma_f32_16x16x32_bf16(
                    af[i], bfr[j], acc[i][j], 0, 0, 0);
        __syncthreads();
    }

    if (EPI == 4) {
        // Phase 1: dump raw acc to LDS scoreboard S[128][128] (f32, swizzled
        // col' = (col+row)&127). acc dies here -> no spill in K-loop.
        float* S = (float*)SMEM;
#pragma unroll
        for (int i = 0; i < FM; ++i) {
            int rbase = wm * (TILE / 2) + i * 16 + (lane >> 4) * 4;
#pragma unroll
            for (int j = 0; j < FM; ++j) {
                int lcol = wn * (TILE / 2) + j * 16 + l15;
#pragma unroll
                for (int r = 0; r < 4; ++r) {
                    int row = rbase + r;
                    S[row * 128 + ((lcol + row) & 127)] = acc[i][j][r];
                }
            }
        }
        __syncthreads();

        // Phase 2: one (row, col-group) pair per thread-iteration.
        // pair p: ml = p & 127 (local row), c = p >> 7 (local 16-col group).
        double local = 0.0;
        const float* LOG_A = sched;
        const float* LOG_1M_A = sched + 1000;
        const float* LOG_CA = sched + 2000;
        const float* LOG_1M_CA = sched + 3000;
#pragma unroll
        for (int it = 0; it < 4; ++it) {
            int p = it * 256 + tid;
            int ml = p & 127, cg = p >> 7;
            int colbase = n0 + cg * 16;
            if (colbase >= 400) continue;     // zero-pad cols
            int m = m0 + ml;
            float ocv[16];
#pragma unroll
            for (int k = 0; k < 16; ++k)
                ocv[k] = S[ml * 128 + ((cg * 16 + k + ml) & 127)] + bias[colbase + k];
            if (colbase == 0) {
                // gaussian block
#pragma unroll
                for (int k = 0; k < 16; ++k) {
                    float d = noise[(size_t)m * 16 + k] - ocv[k];
                    local += (double)(d * d) * (1.0 / (16.0 * BATCH));
                }
            } else {
                int c = (colbase - 16) >> 4;
                int t = t_in[m];
                int xc = x_cat[m * 24 + c];
                int s = hot[m * 24 + c];
                float mx = -3e38f;
#pragma unroll
                for (int k = 0; k < 16; ++k) mx = fmaxf(mx, ocv[k]);
                float sm = 0.0f;
#pragma unroll
                for (int k = 0; k < 16; ++k) sm += expf(ocv[k] - mx);
                float lse = mx + logf(sm);
                int tm1 = (t > 0) ? t - 1 : 0;
                float lca1 = LOG_CA[tm1];
                float l1m1 = LOG_1M_CA[tm1] - LOGKF;
                float la = LOG_A[t];
                float l1a = LOG_1M_A[t] - LOGKF;
                float qh = lae(la, l1a);
                float qo = lae(L30F + la, l1a);
                float levh = (t == 0) ? 0.0f : lae(lca1, l1m1);
                float levo = (t == 0) ? L30F : lae(L30F + lca1, l1m1);
                float un[16], ut[16];
                float mu = -3e38f, mt2 = -3e38f;
#pragma unroll
                for (int k = 0; k < 16; ++k) {
                    float lxh = ocv[k] - lse;
                    float lev = (t == 0) ? lxh : lae(lxh + lca1, l1m1);
                    float q = (k == s) ? qh : qo;
                    un[k] = lev + q;
                    ut[k] = ((k == xc) ? levh : levo) + q;
                    mu = fmaxf(mu, un[k]);
                    mt2 = fmaxf(mt2, ut[k]);
                }
                float su = 0.0f, st = 0.0f;
#pragma unroll
                for (int k = 0; k < 16; ++k) { su += expf(un[k] - mu); st += expf(ut[k] - mt2); }
                float lsu = mu + logf(su), lst = mt2 + logf(st);
                float kl = 0.0f, dn = 0.0f;
#pragma unroll
                for (int k = 0; k < 16; ++k) {
                    float lmp = un[k] - lsu;
                    float ltp = ut[k] - lst;
                    kl += expf(ltp) * (ltp - lmp);
                    dn -= ((k == xc) ? 1.0f : 1e-30f) * lmp;
                }
                float Lt = (t == 0) ? dn : kl;
                local += (double)Lt * (1.0 / (24.0 * BATCH));
            }
        }
        // block reduction (wsum aliases S after sync)
        for (int off = 32; off > 0; off >>= 1)
            local += __shfl_down(local, off);
        __syncthreads();
        double* wred = (double*)SMEM;
        if (lane == 0) wred[wave] = local;
        __syncthreads();
        if (tid == 0)
            atomicAdd(acc_out, wred[0] + wred[1] + wred[2] + wred[3]);
        return;
    }

#pragma unroll
    for (int i = 0; i < FM; ++i) {
        int mbase = m0 + wm * (TILE / 2) + i * 16 + (lane >> 4) * 4;
#pragma unroll
        for (int j = 0; j < FM; ++j) {
            int n = n0 + wn * (TILE / 2) + j * 16 + l15;
            if (n >= Nreal) continue;
            float bv = bias[n];
#pragma unroll
            for (int r = 0; r < 4; ++r) {
                int m = mbase + r;
                if (m >= M) continue;
                float v = acc[i][j][r] + bv;
                if (EPI == 1) v = v / (1.0f + expf(-v));
                if (EPI == 2) v = fmaxf(v, 0.0f);
                if (EPI == 3) v += rowbias[(size_t)tidx[m] * 1024 + n];
                if (EPI == 0)
                    ((float*)Cout)[(size_t)m * Cstride + n] = v;
                else
                    ((__hip_bfloat16*)Cout)[(size_t)m * Cstride + n] = __float2bfloat16(v);
            }
        }
    }
}

// ----------------------- per-row prep: gumbel argmax + build X[B x 416] bf16
// X = [x_num_t (16) | delta-onehot*69.0776 (384) | zeros (16)]
__global__ __launch_bounds__(256) void prep_x(
    const float* __restrict__ x_num, const int* __restrict__ x_cat,
    const int* __restrict__ t_in, const float* __restrict__ noise,
    const float* __restrict__ gum, const float* __restrict__ sched,
    __hip_bfloat16* __restrict__ X, int* __restrict__ hot) {
    __shared__ float xnt[16][16];
    __shared__ int sh_hot[16][24];
    __shared__ int sh_t[16];
    const int b0 = blockIdx.x * 16;
    const int tid = threadIdx.x;
    const float* LOG_CA = sched + 2000;
    const float* LOG_1M_CA = sched + 3000;
    const float* SQ_AC = sched + 4000;
    const float* SQ_1M = sched + 5000;
    if (tid < 16) sh_t[tid] = t_in[b0 + tid];
    __syncthreads();
    {
        int r = tid >> 4, i = tid & 15;
        int t = sh_t[r];
        xnt[r][i] = SQ_AC[t] * x_num[(size_t)(b0 + r) * 16 + i] +
                    SQ_1M[t] * noise[(size_t)(b0 + r) * 16 + i];
    }
    for (int task = tid; task < 16 * 24; task += 256) {
        int r = task / 24, c = task - r * 24;
        int t = sh_t[r];
        int xc = x_cat[(size_t)(b0 + r) * 24 + c];
        float l1 = LOG_1M_CA[t] - LOGKF;
        float lca = LOG_CA[t];
        float vh = lae(lca, l1);
        float vo = lae(L30F + lca, l1);
        const float* gu = gum + (size_t)(b0 + r) * 384 + c * 16;
        float best = -3.0e38f;
        int bi = 0;
#pragma unroll
        for (int k = 0; k < 16; ++k) {
            float g = -logf(-logf(gu[k] + 1e-30f) + 1e-30f);
            float v = g + ((k == xc) ? vh : vo);
            if (v > best) { best = v; bi = k; }
        }
        sh_hot[r][c] = bi;
        hot[(size_t)(b0 + r) * 24 + c] = bi;
    }
    __syncthreads();
    const float DELTA = 69.07755279f;  // -L30F
#pragma unroll
    for (int it = 0; it < 4; ++it) {
        int idx = it * 256 + tid;          // need 16*52 = 832 short8 stores
        if (idx < 832) {
            int r = idx / 52, jc = idx - r * 52;
            int j0 = jc * 8;
            __hip_bfloat16 v[8];
#pragma unroll
            for (int qq = 0; qq < 8; ++qq) {
                int j = j0 + qq;
                float f = 0.0f;
                if (j < 16) {
                    f = xnt[r][j];
                } else if (j < 400) {
                    int c = (j - 16) >> 4, k = (j - 16) & 15;
                    f = (sh_hot[r][c] == k) ? DELTA : 0.0f;
                }
                v[qq] = __float2bfloat16(f);
            }
            *(short8*)(X + (size_t)(b0 + r) * 416 + j0) = *(const short8*)v;
        }
    }
}

__global__ void finalize_kernel(const double* __restrict__ acc,
                                const float* __restrict__ sched,
                                float* __restrict__ out) {
    // kl_prior is identical for every (sample, category): add once.
    float lcaT = sched[2999];
    float l1mT = sched[3999] - LOGKF;
    float ph = lae(lcaT, l1mT);
    float po = lae(L30F + lcaT, l1mT);
    float prior = expf(ph) * (ph + LOGKF) + 15.0f * expf(po) * (po + LOGKF);
    out[0] = (float)(*acc + (double)prior);
}

extern "C" void kernel_launch(void* const* d_in, const int* in_sizes, int n_in,
                              void* d_out, int out_size, void* d_ws, size_t ws_size,
                              hipStream_t stream) {
    const float* x_num  = (const float*)d_in[0];
    const int*   x_cat  = (const int*)d_in[1];
    const int*   t_in   = (const int*)d_in[2];
    const float* noise  = (const float*)d_in[3];
    const float* gum    = (const float*)d_in[4];
    const float* te_w1  = (const float*)d_in[5];
    const float* te_b1  = (const float*)d_in[6];
    const float* te_w2  = (const float*)d_in[7];
    const float* te_b2  = (const float*)d_in[8];
    const float* proj_w = (const float*)d_in[9];
    const float* proj_b = (const float*)d_in[10];
    const float* mlp_w1 = (const float*)d_in[11];
    const float* mlp_b1 = (const float*)d_in[12];
    const float* mlp_w2 = (const float*)d_in[13];
    const float* mlp_b2 = (const float*)d_in[14];
    float* out = (float*)d_out;

    char* w = (char*)d_ws;
    size_t off = 0;
    auto alloc = [&](size_t bytes) {
        void* p = w + off;
        off += (bytes + 1023) & ~(size_t)1023;
        return p;
    };
    double* acc     = (double*)alloc(1024);
    float* sched    = (float*)alloc(6 * 1000 * 4);
    int*   hot      = (int*)alloc((size_t)BATCH * 24 * 4);
    float* colconst = (float*)alloc(1024 * 4);
    __hip_bfloat16* E0   = (__hip_bfloat16*)alloc((size_t)1024 * 1024 * 2);
    __hip_bfloat16* E1   = (__hip_bfloat16*)alloc((size_t)1024 * 1024 * 2);
    float* EMB           = (float*)alloc((size_t)1000 * 1024 * 4);
    __hip_bfloat16* tw1t = (__hip_bfloat16*)alloc((size_t)1024 * 1024 * 2);
    __hip_bfloat16* tw2t = (__hip_bfloat16*)alloc((size_t)1024 * 1024 * 2);
    __hip_bfloat16* pwt  = (__hip_bfloat16*)alloc((size_t)1024 * 416 * 2);
    __hip_bfloat16* w1t  = (__hip_bfloat16*)alloc((size_t)1024 * 1024 * 2);
    __hip_bfloat16* w2t  = (__hip_bfloat16*)alloc((size_t)512 * 1024 * 2);
    __hip_bfloat16* X    = (__hip_bfloat16*)alloc((size_t)BATCH * 416 * 2);
    __hip_bfloat16* h    = (__hip_bfloat16*)alloc((size_t)BATCH * 1024 * 2);
    __hip_bfloat16* R    = (__hip_bfloat16*)alloc((size_t)BATCH * 1024 * 2);

    // setup: 5 weight transposes + E0 table + colconst + schedules (one launch)
    setup_all<<<8005, 256, 0, stream>>>(te_w1, te_w2, proj_w, mlp_w1, mlp_w2,
                                        tw1t, tw2t, pwt, w1t, w2t,
                                        E0, proj_w, proj_b, colconst, sched, acc);
    // X + hot
    prep_x<<<BATCH / 16, 256, 0, stream>>>(x_num, x_cat, t_in, noise, gum, sched, X, hot);
    // E1 = silu(E0 @ te_w1 + te_b1)   [bf16 out]
    gemm_mfma<1, 64><<<dim3(16, 16), 256, 0, stream>>>(
        E0, tw1t, te_b1, E1, 1000, 1024, 1024, 1024,
        nullptr, nullptr, nullptr, nullptr, nullptr, nullptr, nullptr, nullptr);
    // EMB = E1 @ te_w2 + te_b2        [f32 out]
    gemm_mfma<0, 64><<<dim3(16, 16), 256, 0, stream>>>(
        E1, tw2t, te_b2, EMB, 1000, 1024, 1024, 1024,
        nullptr, nullptr, nullptr, nullptr, nullptr, nullptr, nullptr, nullptr);
    // h = X @ proj_w^T + colconst + EMB[t]   [bf16 out, K=416]
    gemm_mfma<3, 128><<<dim3(8, 128), 256, 0, stream>>>(
        X, pwt, colconst, h, BATCH, 416, 1024, 1024,
        t_in, EMB, nullptr, nullptr, nullptr, nullptr, nullptr, nullptr);
    // R = relu(h @ mlp_w1 + mlp_b1)   [bf16 out]
    gemm_mfma<2, 128><<<dim3(8, 128), 256, 0, stream>>>(
        h, w1t, mlp_b1, R, BATCH, 1024, 1024, 1024,
        nullptr, nullptr, nullptr, nullptr, nullptr, nullptr, nullptr, nullptr);
    // fused: (R @ mlp_w2 + mlp_b2) -> LDS scoreboard -> loss (no store)
    gemm_mfma<4, 128><<<dim3(4, 128), 256, 0, stream>>>(
        R, w2t, mlp_b2, nullptr, BATCH, 1024, 400, 0,
        nullptr, nullptr, x_cat, t_in, hot, noise, sched, acc);
    finalize_kernel<<<1, 1, 0, stream>>>(acc, sched, out);
}

// Round 7
// 345.323 us; speedup vs baseline: 1.9755x; 1.1324x over previous
//
#include <hip/hip_runtime.h>
#include <hip/hip_bf16.h>
#include <math.h>

#define BATCH 16384
#define NCAT 24

// log(1e-30f), log(16)
#define L30F  (-69.07755279f)
#define LOGKF (2.7725887f)

typedef __attribute__((ext_vector_type(8))) short short8;
typedef __attribute__((ext_vector_type(4))) float f32x4;

__device__ __forceinline__ float lae(float a, float b) {
    float m = fmaxf(a, b);
    return m + logf(expf(a - m) + expf(b - m));
}

__device__ __forceinline__ void glds16(const void* g, void* l) {
    __builtin_amdgcn_global_load_lds((const __attribute__((address_space(1))) void*)g,
                                     (__attribute__((address_space(3))) void*)l,
                                     16, 0, 0);
}

__device__ __forceinline__ void glds4(const void* g, void* l) {
    __builtin_amdgcn_global_load_lds((const __attribute__((address_space(1))) void*)g,
                                     (__attribute__((address_space(3))) void*)l,
                                     4, 0, 0);
}

// ------------------- fused setup: 5x weight transpose + E0 + colconst + sched
__global__ __launch_bounds__(256) void setup_all(
    const float* __restrict__ s0, const float* __restrict__ s1,
    const float* __restrict__ s2, const float* __restrict__ s3,
    const float* __restrict__ s4,
    __hip_bfloat16* __restrict__ d0, __hip_bfloat16* __restrict__ d1,
    __hip_bfloat16* __restrict__ d2, __hip_bfloat16* __restrict__ d3,
    __hip_bfloat16* __restrict__ d4,
    __hip_bfloat16* __restrict__ E0, const float* __restrict__ proj_w,
    const float* __restrict__ proj_b, float* __restrict__ colconst,
    float* __restrict__ sched, double* __restrict__ acc) {
    const int bid = blockIdx.x, tid = threadIdx.x;
    if (bid < 4000) {
        // weight transpose: W[K x Nw] f32 -> Wt[Npad x Kpad] bf16 (zero pad)
        const int boff[6] = {0, 1024, 2048, 2464, 3488, 4000};
        const int nxs[5]  = {32, 32, 32, 32, 16};
        const int Ks[5]   = {1024, 1024, 400, 1024, 1024};
        const int Kps[5]  = {1024, 1024, 416, 1024, 1024};
        const int Nws[5]  = {1024, 1024, 1024, 1024, 400};
        const int Nps[5]  = {1024, 1024, 1024, 1024, 512};
        int job = 0;
#pragma unroll
        for (int j = 1; j < 5; ++j) job += (bid >= boff[j]) ? 1 : 0;
        const float* W = (job == 0) ? s0 : (job == 1) ? s1 : (job == 2) ? s2
                         : (job == 3) ? s3 : s4;
        __hip_bfloat16* Wt = (job == 0) ? d0 : (job == 1) ? d1 : (job == 2) ? d2
                             : (job == 3) ? d3 : d4;
        const int lb = bid - boff[job];
        const int K = Ks[job], Kpad = Kps[job], Nw = Nws[job], Npad = Nps[job];
        const int n0 = (lb % nxs[job]) * 32, k0 = (lb / nxs[job]) * 32;
        __shared__ float t[32][33];
        int c = tid & 31, r8 = tid >> 5;
#pragma unroll
        for (int i = 0; i < 32; i += 8) {
            int k = k0 + r8 + i, n = n0 + c;
            t[r8 + i][c] = (n < Nw && k < K) ? W[(size_t)k * Nw + n] : 0.0f;
        }
        __syncthreads();
#pragma unroll
        for (int i = 0; i < 32; i += 8) {
            int n = n0 + r8 + i, k = k0 + c;
            if (n < Npad && k < Kpad) Wt[(size_t)n * Kpad + k] = __float2bfloat16(t[c][r8 + i]);
        }
    } else if (bid < 8000) {
        int gid = (bid - 4000) * 256 + tid;
        int t = gid >> 10, j = gid & 1023;
        int jj = (j < 512) ? j : j - 512;
        float freq = expf(-logf(10000.0f) * (float)jj / 512.0f);
        float arg = (float)t * freq;
        E0[gid] = __float2bfloat16((j < 512) ? cosf(arg) : sinf(arg));
    } else if (bid < 8004) {
        int j = (bid - 8000) * 256 + tid;
        float s = 0.0f;
        for (int r = 16; r < 400; ++r) s += proj_w[(size_t)r * 1024 + j];
        colconst[j] = proj_b[j] + L30F * s;
    } else {
        __shared__ double la_s[1000];
        __shared__ double lca_s[1000];
        const double PI = 3.14159265358979323846;
        for (int i = tid; i < 1000; i += 256) {
            double u0 = ((double)i / 1000.0 + 0.008) / 1.008 * PI * 0.5;
            double u1 = ((double)(i + 1) / 1000.0 + 0.008) / 1.008 * PI * 0.5;
            double c0 = cos(u0), c1 = cos(u1);
            double beta = 1.0 - (c1 * c1) / (c0 * c0);
            if (beta > 0.999) beta = 0.999;
            la_s[i] = log(1.0 - beta);
        }
        __syncthreads();
        if (tid == 0) {
            double run = 0.0;
            for (int i = 0; i < 1000; ++i) { run += la_s[i]; lca_s[i] = run; }
            *acc = 0.0;
        }
        __syncthreads();
        for (int i = tid; i < 1000; i += 256) {
            double la = la_s[i], lca = lca_s[i];
            sched[i]        = (float)la;
            sched[1000 + i] = (float)log(1.0 - exp(la) + 1e-40);
            sched[2000 + i] = (float)lca;
            sched[3000 + i] = (float)log(1.0 - exp(lca) + 1e-40);
            sched[4000 + i] = (float)sqrt(exp(lca));
            sched[5000 + i] = (float)sqrt(1.0 - exp(lca));
        }
    }
}

// ------------------------------------------------------------ bf16 MFMA GEMM
// C[M,Nreal] = epi(A[M,Kd] @ Bt^T + bias), A row-major bf16, Bt [Npad x Kd] bf16.
// TILE x TILE block tile, BK=32, 4 waves (2x2), FM x FM frags of 16x16x32 MFMA.
// XCD-aware swizzle. EPI: 0 = f32 store, 1 = silu + bf16, 2 = relu + bf16,
// 3 = +embrow[t[m]][n] (bf16 table, gathered into LDS under the K-loop) + bf16,
// 4 = fused loss: acc -> LDS scoreboard -> per-(row,cat) loss (no store),
// 5 = plain bf16 store.
template <int EPI, int TILE>
__global__ __launch_bounds__(256) void gemm_mfma(
    const __hip_bfloat16* __restrict__ A, const __hip_bfloat16* __restrict__ Bt,
    const float* __restrict__ bias, void* __restrict__ Cout,
    int M, int Kd, int Nreal, int Cstride,
    const int* __restrict__ tidx, const float* __restrict__ rowbias,
    const int* __restrict__ x_cat, const int* __restrict__ t_in,
    const int* __restrict__ hot, const float* __restrict__ noise,
    const float* __restrict__ sched, double* __restrict__ acc_out) {
    constexpr int FM  = TILE / 32;   // MFMA frags per wave per dim
    constexpr int CPM = TILE / 16;   // 16-row staging chunks per matrix
    constexpr int CPW = TILE / 32;   // staging chunks per wave
    constexpr int STAGE = 4 * TILE * 32;  // As+Bs bytes
    constexpr int SMEM_BYTES = (EPI == 4) ? 65536
                               : (EPI == 3) ? (STAGE + TILE * TILE * 2)
                               : STAGE;
    __shared__ __align__(16) char SMEM[SMEM_BYTES];
    __hip_bfloat16* As = (__hip_bfloat16*)SMEM;
    __hip_bfloat16* Bs = As + TILE * 32;

    const int tid = threadIdx.x;
    const int lane = tid & 63, wave = tid >> 6;
    const int wm = wave >> 1, wn = wave & 1;

    // XCD swizzle (same-m n-blocks consecutive within one XCD)
    int mb, nb;
    {
        int nbx = gridDim.x, nby = gridDim.y;
        int b = blockIdx.y * nbx + blockIdx.x;
        if ((nby & 7) == 0) {
            int x = b & 7, g = b >> 3;
            nb = g % nbx;
            mb = x + 8 * (g / nbx);
        } else { mb = blockIdx.y; nb = blockIdx.x; }
    }
    const int m0 = mb * TILE, n0 = nb * TILE;

    const __hip_bfloat16* gsrc[CPW];
    char* ldst[CPW];
#pragma unroll
    for (int ii = 0; ii < CPW; ++ii) {
        int gc = wave * CPW + ii;
        int mat = gc / CPM, rem = gc % CPM;
        int row = rem * 16 + (lane >> 2);
        int col = (lane & 3) * 8;
        if (mat == 0) {
            int r = m0 + row; if (r > M - 1) r = M - 1;   // clamp; stores guarded
            gsrc[ii] = A + (size_t)r * Kd + col;
            ldst[ii] = (char*)As + rem * 1024;
        } else {
            int r = n0 + row;                             // Bt padded to tile
            gsrc[ii] = Bt + (size_t)r * Kd + col;
            ldst[ii] = (char*)Bs + rem * 1024;
        }
    }

    // EPI==3: gather this block's 128 EMB rows (bf16) into LDS. Issued before
    // the K-loop; the loop's first vmcnt(0)+barrier drains them -> latency is
    // hidden under MFMA instead of serialized in the epilogue.
    if (EPI == 3) {
        char* LE = SMEM + STAGE;
        const __hip_bfloat16* embp = (const __hip_bfloat16*)rowbias;
        for (int r = wave * (TILE / 4); r < (wave + 1) * (TILE / 4); ++r) {
            int trow = tidx[m0 + r];   // loop-uniform -> scalarized
            glds4((const char*)(embp + (size_t)trow * 1024 + n0), LE + r * (TILE * 2));
        }
    }

    f32x4 acc[FM][FM] = {};
    const int q8 = (lane >> 4) * 8;
    const int l15 = lane & 15;

    for (int k0 = 0; k0 < Kd; k0 += 32) {
#pragma unroll
        for (int ii = 0; ii < CPW; ++ii) glds16(gsrc[ii] + k0, ldst[ii]);
        __syncthreads();
        short8 af[FM], bfr[FM];
#pragma unroll
        for (int i = 0; i < FM; ++i) {
            af[i]  = *(const short8*)(As + (size_t)(wm * (TILE / 2) + i * 16 + l15) * 32 + q8);
            bfr[i] = *(const short8*)(Bs + (size_t)(wn * (TILE / 2) + i * 16 + l15) * 32 + q8);
        }
#pragma unroll
        for (int i = 0; i < FM; ++i)
#pragma unroll
            for (int j = 0; j < FM; ++j)
                acc[i][j] = __builtin_amdgcn_mfma_f32_16x16x32_bf16(
                    af[i], bfr[j], acc[i][j], 0, 0, 0);
        __syncthreads();
    }

    if (EPI == 4) {
        // Phase 1: dump raw acc to LDS scoreboard S[128][128] (f32, swizzled
        // col' = (col+row)&127). acc dies here -> no spill in K-loop.
        float* S = (float*)SMEM;
#pragma unroll
        for (int i = 0; i < FM; ++i) {
            int rbase = wm * (TILE / 2) + i * 16 + (lane >> 4) * 4;
#pragma unroll
            for (int j = 0; j < FM; ++j) {
                int lcol = wn * (TILE / 2) + j * 16 + l15;
#pragma unroll
                for (int r = 0; r < 4; ++r) {
                    int row = rbase + r;
                    S[row * 128 + ((lcol + row) & 127)] = acc[i][j][r];
                }
            }
        }
        __syncthreads();

        // Phase 2: one (row, col-group) pair per thread-iteration.
        double local = 0.0;
        const float* LOG_A = sched;
        const float* LOG_1M_A = sched + 1000;
        const float* LOG_CA = sched + 2000;
        const float* LOG_1M_CA = sched + 3000;
#pragma unroll
        for (int it = 0; it < 4; ++it) {
            int p = it * 256 + tid;
            int ml = p & 127, cg = p >> 7;
            int colbase = n0 + cg * 16;
            if (colbase >= 400) continue;     // zero-pad cols
            int m = m0 + ml;
            float ocv[16];
#pragma unroll
            for (int k = 0; k < 16; ++k)
                ocv[k] = S[ml * 128 + ((cg * 16 + k + ml) & 127)] + bias[colbase + k];
            if (colbase == 0) {
                // gaussian block
#pragma unroll
                for (int k = 0; k < 16; ++k) {
                    float d = noise[(size_t)m * 16 + k] - ocv[k];
                    local += (double)(d * d) * (1.0 / (16.0 * BATCH));
                }
            } else {
                int c = (colbase - 16) >> 4;
                int t = t_in[m];
                int xc = x_cat[m * 24 + c];
                int s = hot[m * 24 + c];
                float mx = -3e38f;
#pragma unroll
                for (int k = 0; k < 16; ++k) mx = fmaxf(mx, ocv[k]);
                float sm = 0.0f;
#pragma unroll
                for (int k = 0; k < 16; ++k) sm += expf(ocv[k] - mx);
                float lse = mx + logf(sm);
                int tm1 = (t > 0) ? t - 1 : 0;
                float lca1 = LOG_CA[tm1];
                float l1m1 = LOG_1M_CA[tm1] - LOGKF;
                float la = LOG_A[t];
                float l1a = LOG_1M_A[t] - LOGKF;
                float qh = lae(la, l1a);
                float qo = lae(L30F + la, l1a);
                float levh = (t == 0) ? 0.0f : lae(lca1, l1m1);
                float levo = (t == 0) ? L30F : lae(L30F + lca1, l1m1);
                float un[16], ut[16];
                float mu = -3e38f, mt2 = -3e38f;
#pragma unroll
                for (int k = 0; k < 16; ++k) {
                    float lxh = ocv[k] - lse;
                    float lev = (t == 0) ? lxh : lae(lxh + lca1, l1m1);
                    float q = (k == s) ? qh : qo;
                    un[k] = lev + q;
                    ut[k] = ((k == xc) ? levh : levo) + q;
                    mu = fmaxf(mu, un[k]);
                    mt2 = fmaxf(mt2, ut[k]);
                }
                float su = 0.0f, st = 0.0f;
#pragma unroll
                for (int k = 0; k < 16; ++k) { su += expf(un[k] - mu); st += expf(ut[k] - mt2); }
                float lsu = mu + logf(su), lst = mt2 + logf(st);
                float kl = 0.0f, dn = 0.0f;
#pragma unroll
                for (int k = 0; k < 16; ++k) {
                    float lmp = un[k] - lsu;
                    float ltp = ut[k] - lst;
                    kl += expf(ltp) * (ltp - lmp);
                    dn -= ((k == xc) ? 1.0f : 1e-30f) * lmp;
                }
                float Lt = (t == 0) ? dn : kl;
                local += (double)Lt * (1.0 / (24.0 * BATCH));
            }
        }
        // block reduction (wred aliases S after sync)
        for (int off = 32; off > 0; off >>= 1)
            local += __shfl_down(local, off);
        __syncthreads();
        double* wred = (double*)SMEM;
        if (lane == 0) wred[wave] = local;
        __syncthreads();
        if (tid == 0)
            atomicAdd(acc_out, wred[0] + wred[1] + wred[2] + wred[3]);
        return;
    }

    const __hip_bfloat16* LE = (const __hip_bfloat16*)(SMEM + STAGE);
#pragma unroll
    for (int i = 0; i < FM; ++i) {
        int mlbase = wm * (TILE / 2) + i * 16 + (lane >> 4) * 4;
#pragma unroll
        for (int j = 0; j < FM; ++j) {
            int nl = wn * (TILE / 2) + j * 16 + l15;
            int n = n0 + nl;
            if (n >= Nreal) continue;
            float bv = bias[n];
#pragma unroll
            for (int r = 0; r < 4; ++r) {
                int ml = mlbase + r;
                int m = m0 + ml;
                if (m >= M) continue;
                float v = acc[i][j][r] + bv;
                if (EPI == 1) v = v / (1.0f + expf(-v));
                if (EPI == 2) v = fmaxf(v, 0.0f);
                if (EPI == 3) v += __bfloat162float(LE[ml * TILE + nl]);
                if (EPI == 0)
                    ((float*)Cout)[(size_t)m * Cstride + n] = v;
                else
                    ((__hip_bfloat16*)Cout)[(size_t)m * Cstride + n] = __float2bfloat16(v);
            }
        }
    }
}

// ----------------------- per-row prep: gumbel argmax + build X[B x 416] bf16
// X = [x_num_t (16) | delta-onehot*69.0776 (384) | zeros (16)]
__global__ __launch_bounds__(256) void prep_x(
    const float* __restrict__ x_num, const int* __restrict__ x_cat,
    const int* __restrict__ t_in, const float* __restrict__ noise,
    const float* __restrict__ gum, const float* __restrict__ sched,
    __hip_bfloat16* __restrict__ X, int* __restrict__ hot) {
    __shared__ float xnt[16][16];
    __shared__ int sh_hot[16][24];
    __shared__ int sh_t[16];
    const int b0 = blockIdx.x * 16;
    const int tid = threadIdx.x;
    const float* LOG_CA = sched + 2000;
    const float* LOG_1M_CA = sched + 3000;
    const float* SQ_AC = sched + 4000;
    const float* SQ_1M = sched + 5000;
    if (tid < 16) sh_t[tid] = t_in[b0 + tid];
    __syncthreads();
    {
        int r = tid >> 4, i = tid & 15;
        int t = sh_t[r];
        xnt[r][i] = SQ_AC[t] * x_num[(size_t)(b0 + r) * 16 + i] +
                    SQ_1M[t] * noise[(size_t)(b0 + r) * 16 + i];
    }
    for (int task = tid; task < 16 * 24; task += 256) {
        int r = task / 24, c = task - r * 24;
        int t = sh_t[r];
        int xc = x_cat[(size_t)(b0 + r) * 24 + c];
        float l1 = LOG_1M_CA[t] - LOGKF;
        float lca = LOG_CA[t];
        float vh = lae(lca, l1);
        float vo = lae(L30F + lca, l1);
        const float* gu = gum + (size_t)(b0 + r) * 384 + c * 16;
        float best = -3.0e38f;
        int bi = 0;
#pragma unroll
        for (int k = 0; k < 16; ++k) {
            float g = -logf(-logf(gu[k] + 1e-30f) + 1e-30f);
            float v = g + ((k == xc) ? vh : vo);
            if (v > best) { best = v; bi = k; }
        }
        sh_hot[r][c] = bi;
        hot[(size_t)(b0 + r) * 24 + c] = bi;
    }
    __syncthreads();
    const float DELTA = 69.07755279f;  // -L30F
#pragma unroll
    for (int it = 0; it < 4; ++it) {
        int idx = it * 256 + tid;          // need 16*52 = 832 short8 stores
        if (idx < 832) {
            int r = idx / 52, jc = idx - r * 52;
            int j0 = jc * 8;
            __hip_bfloat16 v[8];
#pragma unroll
            for (int qq = 0; qq < 8; ++qq) {
                int j = j0 + qq;
                float f = 0.0f;
                if (j < 16) {
                    f = xnt[r][j];
                } else if (j < 400) {
                    int c = (j - 16) >> 4, k = (j - 16) & 15;
                    f = (sh_hot[r][c] == k) ? DELTA : 0.0f;
                }
                v[qq] = __float2bfloat16(f);
            }
            *(short8*)(X + (size_t)(b0 + r) * 416 + j0) = *(const short8*)v;
        }
    }
}

__global__ void finalize_kernel(const double* __restrict__ acc,
                                const float* __restrict__ sched,
                                float* __restrict__ out) {
    // kl_prior is identical for every (sample, category): add once.
    float lcaT = sched[2999];
    float l1mT = sched[3999] - LOGKF;
    float ph = lae(lcaT, l1mT);
    float po = lae(L30F + lcaT, l1mT);
    float prior = expf(ph) * (ph + LOGKF) + 15.0f * expf(po) * (po + LOGKF);
    out[0] = (float)(*acc + (double)prior);
}

extern "C" void kernel_launch(void* const* d_in, const int* in_sizes, int n_in,
                              void* d_out, int out_size, void* d_ws, size_t ws_size,
                              hipStream_t stream) {
    const float* x_num  = (const float*)d_in[0];
    const int*   x_cat  = (const int*)d_in[1];
    const int*   t_in   = (const int*)d_in[2];
    const float* noise  = (const float*)d_in[3];
    const float* gum    = (const float*)d_in[4];
    const float* te_w1  = (const float*)d_in[5];
    const float* te_b1  = (const float*)d_in[6];
    const float* te_w2  = (const float*)d_in[7];
    const float* te_b2  = (const float*)d_in[8];
    const float* proj_w = (const float*)d_in[9];
    const float* proj_b = (const float*)d_in[10];
    const float* mlp_w1 = (const float*)d_in[11];
    const float* mlp_b1 = (const float*)d_in[12];
    const float* mlp_w2 = (const float*)d_in[13];
    const float* mlp_b2 = (const float*)d_in[14];
    float* out = (float*)d_out;

    char* w = (char*)d_ws;
    size_t off = 0;
    auto alloc = [&](size_t bytes) {
        void* p = w + off;
        off += (bytes + 1023) & ~(size_t)1023;
        return p;
    };
    double* acc     = (double*)alloc(1024);
    float* sched    = (float*)alloc(6 * 1000 * 4);
    int*   hot      = (int*)alloc((size_t)BATCH * 24 * 4);
    float* colconst = (float*)alloc(1024 * 4);
    __hip_bfloat16* E0    = (__hip_bfloat16*)alloc((size_t)1024 * 1024 * 2);
    __hip_bfloat16* E1    = (__hip_bfloat16*)alloc((size_t)1024 * 1024 * 2);
    __hip_bfloat16* EMBb  = (__hip_bfloat16*)alloc((size_t)1000 * 1024 * 2);
    __hip_bfloat16* tw1t  = (__hip_bfloat16*)alloc((size_t)1024 * 1024 * 2);
    __hip_bfloat16* tw2t  = (__hip_bfloat16*)alloc((size_t)1024 * 1024 * 2);
    __hip_bfloat16* pwt   = (__hip_bfloat16*)alloc((size_t)1024 * 416 * 2);
    __hip_bfloat16* w1t   = (__hip_bfloat16*)alloc((size_t)1024 * 1024 * 2);
    __hip_bfloat16* w2t   = (__hip_bfloat16*)alloc((size_t)512 * 1024 * 2);
    __hip_bfloat16* X     = (__hip_bfloat16*)alloc((size_t)BATCH * 416 * 2);
    __hip_bfloat16* h     = (__hip_bfloat16*)alloc((size_t)BATCH * 1024 * 2);
    __hip_bfloat16* R     = (__hip_bfloat16*)alloc((size_t)BATCH * 1024 * 2);

    // setup: 5 weight transposes + E0 table + colconst + schedules (one launch)
    setup_all<<<8005, 256, 0, stream>>>(te_w1, te_w2, proj_w, mlp_w1, mlp_w2,
                                        tw1t, tw2t, pwt, w1t, w2t,
                                        E0, proj_w, proj_b, colconst, sched, acc);
    // X + hot
    prep_x<<<BATCH / 16, 256, 0, stream>>>(x_num, x_cat, t_in, noise, gum, sched, X, hot);
    // E1 = silu(E0 @ te_w1 + te_b1)   [bf16 out]
    gemm_mfma<1, 64><<<dim3(16, 16), 256, 0, stream>>>(
        E0, tw1t, te_b1, E1, 1000, 1024, 1024, 1024,
        nullptr, nullptr, nullptr, nullptr, nullptr, nullptr, nullptr, nullptr);
    // EMBb = E1 @ te_w2 + te_b2       [bf16 out]
    gemm_mfma<5, 64><<<dim3(16, 16), 256, 0, stream>>>(
        E1, tw2t, te_b2, EMBb, 1000, 1024, 1024, 1024,
        nullptr, nullptr, nullptr, nullptr, nullptr, nullptr, nullptr, nullptr);
    // h = X @ proj_w^T + colconst + EMBb[t]   [bf16 out, K=416, LDS-gathered emb]
    gemm_mfma<3, 128><<<dim3(8, 128), 256, 0, stream>>>(
        X, pwt, colconst, h, BATCH, 416, 1024, 1024,
        t_in, (const float*)EMBb, nullptr, nullptr, nullptr, nullptr, nullptr, nullptr);
    // R = relu(h @ mlp_w1 + mlp_b1)   [bf16 out]
    gemm_mfma<2, 128><<<dim3(8, 128), 256, 0, stream>>>(
        h, w1t, mlp_b1, R, BATCH, 1024, 1024, 1024,
        nullptr, nullptr, nullptr, nullptr, nullptr, nullptr, nullptr, nullptr);
    // fused: (R @ mlp_w2 + mlp_b2) -> LDS scoreboard -> loss (no store)
    gemm_mfma<4, 128><<<dim3(4, 128), 256, 0, stream>>>(
        R, w2t, mlp_b2, nullptr, BATCH, 1024, 400, 0,
        nullptr, nullptr, x_cat, t_in, hot, noise, sched, acc);
    finalize_kernel<<<1, 1, 0, stream>>>(acc, sched, out);
}